// Round 12
// baseline (802.027 us; speedup 1.0000x reference)
//
#include <hip/hip_runtime.h>

#define N_NODES 100000
#define N_EDGES 1600000
#define N_GRAPHS 1024
#define D 128
#define NL 3
#define BN_EPS 1e-5f
#define BG 196                                  // dst nodes per bucket
#define NB ((N_NODES + BG - 1) / BG)            // 511 buckets
#define EPB 4096                                // edges per partition block
#define NREP 64                                 // stats replica banks

typedef __attribute__((ext_vector_type(8))) short bf16x8;
typedef __attribute__((ext_vector_type(4))) float f32x4;

__device__ __forceinline__ unsigned short f2b(float f) {
    unsigned int u = __float_as_uint(f);
    u += 0x7fff + ((u >> 16) & 1);   // round to nearest even
    return (unsigned short)(u >> 16);
}
__device__ __forceinline__ float b2f(unsigned short b) {
    return __uint_as_float(((unsigned int)b) << 16);
}

__device__ __forceinline__ int geti(const void* p, long long i, int f64) {
    return f64 ? (int)((const long long*)p)[i] : ((const int*)p)[i];
}

// ------- weight prep: Wt[m][n][k] = bf16(W[m][k][n]); block(0,0) also detects
// the edge-index dtype (int64 vs int32) into *flag.
__global__ void k_wprep(const float* __restrict__ W1, const float* __restrict__ W2,
                        unsigned short* __restrict__ Wt, const void* ei, int* flag) {
    int m = blockIdx.y;
    int k = blockIdx.x;
    int n = threadIdx.x;
    const float* src = (m < NL) ? (W1 + (size_t)m * D * D) : (W2 + (size_t)(m - NL) * D * D);
    Wt[(size_t)m * D * D + n * D + k] = f2b(src[k * D + n]);
    if (blockIdx.x == 0 && blockIdx.y == 0 && threadIdx.x < 64) {
        int t = threadIdx.x;
        const int* p = (const int*)ei;
        int acc = p[2 * t + 1] | p[2 * (t + 64) + 1];
        unsigned long long b = __ballot(acc != 0);
        if (t == 0) *flag = (b == 0ULL) ? 1 : 0;
    }
}

// ---- graph boundaries from sorted batch: gstart[g] = first node of graph g;
// gstart[N_GRAPHS] = N_NODES. Range-fill at transitions handles empty graphs.
__global__ __launch_bounds__(256) void k_gbound(const void* batch, const int* __restrict__ flag,
                                                int* __restrict__ gstart) {
    int f = *flag;
    int i = blockIdx.x * 256 + threadIdx.x;
    if (i >= N_NODES) return;
    int b1 = geti(batch, i, f);
    if (i == 0) {
        for (int g = 0; g <= b1; ++g) gstart[g] = 0;
    } else {
        int b0 = geti(batch, i - 1, f);
        for (int g = b0 + 1; g <= b1; ++g) gstart[g] = i;
    }
    if (i == N_NODES - 1) {
        for (int g = b1 + 1; g <= N_GRAPHS; ++g) gstart[g] = N_NODES;
    }
}

// ---- bucket-level edge count: LDS hist over 511 buckets, one flush/block ----
__global__ __launch_bounds__(256) void k_bcount(const void* ei, const int* __restrict__ flag,
                                                int* __restrict__ bcnt) {
    __shared__ int hist[NB];
    int tid = threadIdx.x;
    long long e0 = (long long)blockIdx.x * EPB;
    int f = *flag;
    for (int b = tid; b < NB; b += 256) hist[b] = 0;
    __syncthreads();
#pragma unroll
    for (int i = 0; i < EPB / 256; ++i) {
        long long e = e0 + i * 256 + tid;
        if (e < N_EDGES) {
            int d = geti(ei, (long long)N_EDGES + e, f);
            atomicAdd(&hist[d / BG], 1);
        }
    }
    __syncthreads();
    for (int b = tid; b < NB; b += 256) {
        int h = hist[b];
        if (h) atomicAdd(&bcnt[b], h);
    }
}

// ---- bucket prefix scan (511 entries, 1 block): bbase/gcur; rowp[N]=E ----
__global__ void k_bscan(const int* __restrict__ bcnt, int* __restrict__ bbase,
                        int* __restrict__ gcur, int* __restrict__ rowp) {
    __shared__ int wtot[4];
    int tid = threadIdx.x;           // 256
    int lane = tid & 63, w = tid >> 6;
    int i0 = 2 * tid, i1 = 2 * tid + 1;
    int a = (i0 < NB) ? bcnt[i0] : 0;
    int b = (i1 < NB) ? bcnt[i1] : 0;
    int p = a + b;
    int incl = p;
    for (int off = 1; off < 64; off <<= 1) {
        int v = __shfl_up(incl, off, 64);
        if (lane >= off) incl += v;
    }
    if (lane == 63) wtot[w] = incl;
    __syncthreads();
    int woff = 0;
    for (int w2 = 0; w2 < w; ++w2) woff += wtot[w2];
    int ex = woff + incl - p;
    if (i0 <= NB) { bbase[i0] = ex; gcur[i0] = ex; }
    if (i1 <= NB) { bbase[i1] = ex + a; gcur[i1] = ex + a; }
    if (tid == 0) rowp[N_NODES] = N_EDGES;
}

// ---- partition edges into NB coarse dst-buckets, packed (dl<<17|src) --------
__global__ __launch_bounds__(256) void k_part(const void* ei, const int* __restrict__ flag,
                                              int* __restrict__ gcur,
                                              unsigned int* __restrict__ tmp) {
    __shared__ int hist[NB + 1];
    __shared__ int cur[NB + 1];
    int tid = threadIdx.x;
    long long e0 = (long long)blockIdx.x * EPB;
    int f = *flag;
    for (int b = tid; b < NB; b += 256) hist[b] = 0;
    __syncthreads();
#pragma unroll
    for (int i = 0; i < EPB / 256; ++i) {
        long long e = e0 + i * 256 + tid;
        if (e < N_EDGES) {
            int d = geti(ei, (long long)N_EDGES + e, f);
            atomicAdd(&hist[d / BG], 1);
        }
    }
    __syncthreads();
    for (int b = tid; b < NB; b += 256) {
        int h = hist[b];
        cur[b] = h ? atomicAdd(&gcur[b], h) : 0;
    }
    __syncthreads();
#pragma unroll
    for (int i = 0; i < EPB / 256; ++i) {
        long long e = e0 + i * 256 + tid;
        if (e < N_EDGES) {
            int d = geti(ei, (long long)N_EDGES + e, f);
            int s = geti(ei, e, f);
            int b = d / BG;
            int pos = atomicAdd(&cur[b], 1);
            tmp[pos] = ((unsigned int)(d - b * BG) << 17) | (unsigned int)s;
        }
    }
}

// ---- per-bucket: build deg in LDS, local prefix -> rowp, scatter to eidx ----
__global__ __launch_bounds__(256) void k_fscat(const unsigned int* __restrict__ tmp,
                                               const int* __restrict__ bbase,
                                               int* __restrict__ rowp,
                                               int* __restrict__ eidx) {
    __shared__ int deg[BG];
    __shared__ int cur[BG];
    __shared__ int wtot[4];
    __shared__ int s_se[2];
    int b = blockIdx.x;
    int nb = b * BG;
    int nn = min(BG, N_NODES - nb);
    int tid = threadIdx.x;
    int lane = tid & 63, w = tid >> 6;
    if (tid < nn) deg[tid] = 0;
    if (tid == 0) s_se[0] = bbase[b];
    if (tid == 1) s_se[1] = bbase[b + 1];
    __syncthreads();
    int s = s_se[0], e = s_se[1];
    // pass 1: per-dst counts
    for (int t = s + tid; t < e; t += 256) atomicAdd(&deg[tmp[t] >> 17], 1);
    __syncthreads();
    // exclusive prefix over nn (<=196) entries, 4-wave shuffle scan
    int val = (tid < nn) ? deg[tid] : 0;
    int incl = val;
    for (int off = 1; off < 64; off <<= 1) {
        int v = __shfl_up(incl, off, 64);
        if (lane >= off) incl += v;
    }
    if (lane == 63) wtot[w] = incl;
    __syncthreads();
    int woff = 0;
    for (int w2 = 0; w2 < w; ++w2) woff += wtot[w2];
    int ex = s + woff + incl - val;
    if (tid < nn) {
        cur[tid] = ex;
        rowp[nb + tid] = ex;
    }
    __syncthreads();
    // pass 2: scatter within bucket (L2-local)
    for (int t = s + tid; t < e; t += 256) {
        unsigned int u = tmp[t];
        int dl = u >> 17;
        int pos = atomicAdd(&cur[dl], 1);
        eidx[pos] = (int)(u & 0x1FFFF);
    }
}

// ---------------- GEMM0: u0 = bf16(x) @ W1_0 (fp32 A direct, W in LDS) -------
__global__ __launch_bounds__(256) void k_gemm0(const float* __restrict__ x,
                                               const unsigned short* __restrict__ Wt,
                                               unsigned short* __restrict__ ub) {
    __shared__ unsigned short Ws[128 * 136];
    int tid = threadIdx.x;
    int row0 = blockIdx.x * 128;
#pragma unroll
    for (int i = 0; i < 8; ++i) {
        int chunk = tid + 256 * i;
        int n = chunk >> 4;
        int k8 = (chunk & 15) * 8;
        *(bf16x8*)&Ws[n * 136 + k8] = *(const bf16x8*)&Wt[n * 128 + k8];
    }
    __syncthreads();

    int w = tid >> 6, lane = tid & 63, q = lane >> 4, ln = lane & 15;
    int rbase = row0 + (w & 1) * 64, cbase = (w >> 1) * 64;

    f32x4 acc[4][4];
    f32x4 z4 = {0.f, 0.f, 0.f, 0.f};
#pragma unroll
    for (int rt = 0; rt < 4; ++rt)
#pragma unroll
        for (int ct = 0; ct < 4; ++ct) acc[rt][ct] = z4;

#pragma unroll
    for (int ks = 0; ks < 4; ++ks) {
        int ko = ks * 32 + q * 8;
        bf16x8 af[4];
#pragma unroll
        for (int rt = 0; rt < 4; ++rt) {
            int row = rbase + rt * 16 + ln;
            bf16x8 v = {0, 0, 0, 0, 0, 0, 0, 0};
            if (row < N_NODES) {
                float4 p0 = *(const float4*)&x[(size_t)row * 128 + ko];
                float4 p1 = *(const float4*)&x[(size_t)row * 128 + ko + 4];
                v[0] = (short)f2b(p0.x); v[1] = (short)f2b(p0.y);
                v[2] = (short)f2b(p0.z); v[3] = (short)f2b(p0.w);
                v[4] = (short)f2b(p1.x); v[5] = (short)f2b(p1.y);
                v[6] = (short)f2b(p1.z); v[7] = (short)f2b(p1.w);
            }
            af[rt] = v;
        }
        bf16x8 bfr[4];
#pragma unroll
        for (int ct = 0; ct < 4; ++ct)
            bfr[ct] = *(bf16x8*)&Ws[(cbase + ct * 16 + ln) * 136 + ko];
#pragma unroll
        for (int rt = 0; rt < 4; ++rt)
#pragma unroll
            for (int ct = 0; ct < 4; ++ct)
                acc[rt][ct] = __builtin_amdgcn_mfma_f32_16x16x32_bf16(af[rt], bfr[ct],
                                                                      acc[rt][ct], 0, 0, 0);
    }
#pragma unroll
    for (int rt = 0; rt < 4; ++rt) {
        int gr0 = rbase + rt * 16 + q * 4;
#pragma unroll
        for (int i = 0; i < 4; ++i) {
            int gr = gr0 + i;
            if (gr < N_NODES) {
#pragma unroll
                for (int ct = 0; ct < 4; ++ct)
                    ub[(size_t)gr * 128 + cbase + ct * 16 + ln] = f2b(acc[rt][ct][i]);
            }
        }
    }
}

// ---- aggregation + fused BN stats: z = u_i + sum_j u_j; stats += (z, z^2) ---
// Per-node gather body identical to the proven BW-floor version. 1024-thread
// blocks: 16 waves x 4 nodes = 64 nodes/block -> 1563 blocks -> 0.4M flush
// atomics/layer (4x fewer than round 10; atomic cost model: 63.2us + 16.4ns
// per flush atomic fits rounds 9/10/11 within 2%). LDS stats + one 256-atomic
// flush per block into NREP replica banks.
__global__ __launch_bounds__(1024) void k_agz(const unsigned short* __restrict__ ub,
                                              const int* __restrict__ rowp,
                                              const int* __restrict__ eidx,
                                              unsigned short* __restrict__ zb,
                                              float* __restrict__ stats) {
    __shared__ float s_sum[128];
    __shared__ float s_sq[128];
    int tid = threadIdx.x;
    int wid = tid >> 6;           // 0..15
    int lane = tid & 63;
    int eg = lane >> 4;           // edge slot 0..3
    int c = lane & 15;            // 16B quad within row (dwords 4c..4c+3)
    if (tid < 128) {
        s_sum[tid] = 0.f;
        s_sq[tid] = 0.f;
    }
    __syncthreads();
    const unsigned int* u1 = (const unsigned int*)ub;   // 64 dwords per row
    int base = blockIdx.x * 64 + wid * 4;
#pragma unroll
    for (int j = 0; j < 4; ++j) {
        int node = base + j;
        if (node < N_NODES) {     // wave-uniform guard
            float ax0 = 0.f, ax1 = 0.f, ax2 = 0.f, ax3 = 0.f;
            float ay0 = 0.f, ay1 = 0.f, ay2 = 0.f, ay3 = 0.f;
            int s = rowp[node], e = rowp[node + 1];
            int i = s;
            for (; i + 7 < e; i += 8) {
                int p0 = eidx[i + eg];
                int p1 = eidx[i + 4 + eg];
                uint4 a = *(const uint4*)&u1[(size_t)p0 * 64 + c * 4];
                uint4 b = *(const uint4*)&u1[(size_t)p1 * 64 + c * 4];
                ax0 += __uint_as_float(a.x << 16) + __uint_as_float(b.x << 16);
                ay0 += __uint_as_float(a.x & 0xffff0000u) + __uint_as_float(b.x & 0xffff0000u);
                ax1 += __uint_as_float(a.y << 16) + __uint_as_float(b.y << 16);
                ay1 += __uint_as_float(a.y & 0xffff0000u) + __uint_as_float(b.y & 0xffff0000u);
                ax2 += __uint_as_float(a.z << 16) + __uint_as_float(b.z << 16);
                ay2 += __uint_as_float(a.z & 0xffff0000u) + __uint_as_float(b.z & 0xffff0000u);
                ax3 += __uint_as_float(a.w << 16) + __uint_as_float(b.w << 16);
                ay3 += __uint_as_float(a.w & 0xffff0000u) + __uint_as_float(b.w & 0xffff0000u);
            }
            for (; i < e; i += 4) {
                int pos = i + eg;
                int valid = pos < e;
                int p0 = eidx[valid ? pos : (e - 1)];
                uint4 a = *(const uint4*)&u1[(size_t)p0 * 64 + c * 4];
                if (valid) {
                    ax0 += __uint_as_float(a.x << 16);
                    ay0 += __uint_as_float(a.x & 0xffff0000u);
                    ax1 += __uint_as_float(a.y << 16);
                    ay1 += __uint_as_float(a.y & 0xffff0000u);
                    ax2 += __uint_as_float(a.z << 16);
                    ay2 += __uint_as_float(a.z & 0xffff0000u);
                    ax3 += __uint_as_float(a.w << 16);
                    ay3 += __uint_as_float(a.w & 0xffff0000u);
                }
            }
            // reduce 4 edge-slot groups; lanes with equal c hold the same features
#pragma unroll
            for (int off = 16; off < 64; off <<= 1) {
                ax0 += __shfl_xor(ax0, off, 64);
                ay0 += __shfl_xor(ay0, off, 64);
                ax1 += __shfl_xor(ax1, off, 64);
                ay1 += __shfl_xor(ay1, off, 64);
                ax2 += __shfl_xor(ax2, off, 64);
                ay2 += __shfl_xor(ay2, off, 64);
                ax3 += __shfl_xor(ax3, off, 64);
                ay3 += __shfl_xor(ay3, off, 64);
            }
            if (eg == 0) {
                uint4 sv = *(const uint4*)&u1[(size_t)node * 64 + c * 4];
                ax0 += __uint_as_float(sv.x << 16);
                ay0 += __uint_as_float(sv.x & 0xffff0000u);
                ax1 += __uint_as_float(sv.y << 16);
                ay1 += __uint_as_float(sv.y & 0xffff0000u);
                ax2 += __uint_as_float(sv.z << 16);
                ay2 += __uint_as_float(sv.z & 0xffff0000u);
                ax3 += __uint_as_float(sv.w << 16);
                ay3 += __uint_as_float(sv.w & 0xffff0000u);
                uint4 o;
                o.x = ((unsigned int)f2b(ay0) << 16) | f2b(ax0);
                o.y = ((unsigned int)f2b(ay1) << 16) | f2b(ax1);
                o.z = ((unsigned int)f2b(ay2) << 16) | f2b(ax2);
                o.w = ((unsigned int)f2b(ay3) << 16) | f2b(ax3);
                *(uint4*)&((unsigned int*)zb)[(size_t)node * 64 + c * 4] = o;
                // stats from the bf16-rounded stored values (matches old zstats)
                float rx, ry;
                rx = b2f((unsigned short)(o.x & 0xffffu)); ry = b2f((unsigned short)(o.x >> 16));
                atomicAdd(&s_sum[c * 8 + 0], rx); atomicAdd(&s_sq[c * 8 + 0], rx * rx);
                atomicAdd(&s_sum[c * 8 + 1], ry); atomicAdd(&s_sq[c * 8 + 1], ry * ry);
                rx = b2f((unsigned short)(o.y & 0xffffu)); ry = b2f((unsigned short)(o.y >> 16));
                atomicAdd(&s_sum[c * 8 + 2], rx); atomicAdd(&s_sq[c * 8 + 2], rx * rx);
                atomicAdd(&s_sum[c * 8 + 3], ry); atomicAdd(&s_sq[c * 8 + 3], ry * ry);
                rx = b2f((unsigned short)(o.z & 0xffffu)); ry = b2f((unsigned short)(o.z >> 16));
                atomicAdd(&s_sum[c * 8 + 4], rx); atomicAdd(&s_sq[c * 8 + 4], rx * rx);
                atomicAdd(&s_sum[c * 8 + 5], ry); atomicAdd(&s_sq[c * 8 + 5], ry * ry);
                rx = b2f((unsigned short)(o.w & 0xffffu)); ry = b2f((unsigned short)(o.w >> 16));
                atomicAdd(&s_sum[c * 8 + 6], rx); atomicAdd(&s_sq[c * 8 + 6], rx * rx);
                atomicAdd(&s_sum[c * 8 + 7], ry); atomicAdd(&s_sq[c * 8 + 7], ry * ry);
            }
        }
    }
    __syncthreads();
    if (tid < 128) {
        float* S = stats + (size_t)(blockIdx.x & (NREP - 1)) * 256;
        atomicAdd(&S[tid], s_sum[tid]);
        atomicAdd(&S[128 + tid], s_sq[tid]);
    }
}

// ---- GEMM2 fused: x = relu(BN(z)@W2+b2); if !LAST also u' = x@W1next -------
// BN(z) staged ONCE per element into Xs (halves BN VALU vs per-wave frag BN);
// both K-loops read A-frags via ds_read_b128. Xs is reused for x between
// stages; Ws is reused for W1next. Stats arrive in NREP replica banks.
template <int LAST>
__global__ __launch_bounds__(256) void k_gemm2f(const unsigned short* __restrict__ zb,
                                                const unsigned short* __restrict__ Wt2,
                                                const unsigned short* __restrict__ Wt1n,
                                                const float* __restrict__ b2,
                                                const float* __restrict__ stats,
                                                const float* __restrict__ gamma,
                                                const float* __restrict__ beta,
                                                unsigned short* __restrict__ outb) {
    __shared__ unsigned short Ws[128 * 136];
    __shared__ unsigned short Xs[128 * 136];
    __shared__ float s_a[128];
    __shared__ float s_b[128];

    int tid = threadIdx.x;
    int row0 = blockIdx.x * 128;

    // stage Ws = W2; compute BN scale/shift from replica banks
#pragma unroll
    for (int i = 0; i < 8; ++i) {
        int chunk = tid + 256 * i;
        int n = chunk >> 4;
        int k8 = (chunk & 15) * 8;
        *(bf16x8*)&Ws[n * 136 + k8] = *(const bf16x8*)&Wt2[n * 128 + k8];
    }
    if (tid < 128) {
        float s1 = 0.f, s2 = 0.f;
#pragma unroll 8
        for (int r = 0; r < NREP; ++r) {
            s1 += stats[(size_t)r * 256 + tid];
            s2 += stats[(size_t)r * 256 + 128 + tid];
        }
        float mu = s1 / (float)N_NODES;
        float var = s2 / (float)N_NODES - mu * mu;
        float sc = rsqrtf(var + BN_EPS) * gamma[tid];
        s_a[tid] = sc;
        s_b[tid] = beta[tid] - mu * sc;
    }
    __syncthreads();

    // stage relu(BN(z)) -> Xs, each element exactly once
#pragma unroll
    for (int i = 0; i < 8; ++i) {
        int chunk = tid + 256 * i;
        int row = chunk >> 4;
        int k8 = (chunk & 15) * 8;
        int gr = row0 + row;
        bf16x8 v = {0, 0, 0, 0, 0, 0, 0, 0};
        if (gr < N_NODES) v = *(const bf16x8*)&zb[(size_t)gr * 128 + k8];
        float4 sc0 = *(const float4*)&s_a[k8];
        float4 sc1 = *(const float4*)&s_a[k8 + 4];
        float4 sh0 = *(const float4*)&s_b[k8];
        float4 sh1 = *(const float4*)&s_b[k8 + 4];
        bf16x8 o;
        o[0] = (short)f2b(fmaxf(b2f((unsigned short)v[0]) * sc0.x + sh0.x, 0.f));
        o[1] = (short)f2b(fmaxf(b2f((unsigned short)v[1]) * sc0.y + sh0.y, 0.f));
        o[2] = (short)f2b(fmaxf(b2f((unsigned short)v[2]) * sc0.z + sh0.z, 0.f));
        o[3] = (short)f2b(fmaxf(b2f((unsigned short)v[3]) * sc0.w + sh0.w, 0.f));
        o[4] = (short)f2b(fmaxf(b2f((unsigned short)v[4]) * sc1.x + sh1.x, 0.f));
        o[5] = (short)f2b(fmaxf(b2f((unsigned short)v[5]) * sc1.y + sh1.y, 0.f));
        o[6] = (short)f2b(fmaxf(b2f((unsigned short)v[6]) * sc1.z + sh1.z, 0.f));
        o[7] = (short)f2b(fmaxf(b2f((unsigned short)v[7]) * sc1.w + sh1.w, 0.f));
        *(bf16x8*)&Xs[row * 136 + k8] = o;
    }
    __syncthreads();

    int w = tid >> 6, lane = tid & 63, q = lane >> 4, ln = lane & 15;
    int lrbase = (w & 1) * 64, cbase = (w >> 1) * 64;

    f32x4 acc[4][4];
    f32x4 z4 = {0.f, 0.f, 0.f, 0.f};
#pragma unroll
    for (int rt = 0; rt < 4; ++rt)
#pragma unroll
        for (int ct = 0; ct < 4; ++ct) acc[rt][ct] = z4;

    // stage 1 K-loop: A from Xs, B from Ws (pure ds_read + MFMA)
#pragma unroll
    for (int ks = 0; ks < 4; ++ks) {
        int ko = ks * 32 + q * 8;
        bf16x8 af[4], bfr[4];
#pragma unroll
        for (int rt = 0; rt < 4; ++rt)
            af[rt] = *(bf16x8*)&Xs[(lrbase + rt * 16 + ln) * 136 + ko];
#pragma unroll
        for (int ct = 0; ct < 4; ++ct)
            bfr[ct] = *(bf16x8*)&Ws[(cbase + ct * 16 + ln) * 136 + ko];
#pragma unroll
        for (int rt = 0; rt < 4; ++rt)
#pragma unroll
            for (int ct = 0; ct < 4; ++ct)
                acc[rt][ct] = __builtin_amdgcn_mfma_f32_16x16x32_bf16(af[rt], bfr[ct],
                                                                      acc[rt][ct], 0, 0, 0);
    }

    float bsv[4];
#pragma unroll
    for (int ct = 0; ct < 4; ++ct) bsv[ct] = b2[cbase + ct * 16 + ln];

    if (LAST) {
        // epilogue straight to global
#pragma unroll
        for (int rt = 0; rt < 4; ++rt) {
            int gr0 = row0 + lrbase + rt * 16 + q * 4;
#pragma unroll
            for (int i = 0; i < 4; ++i) {
                int gr = gr0 + i;
                if (gr < N_NODES) {
#pragma unroll
                    for (int ct = 0; ct < 4; ++ct) {
                        float xv = fmaxf(acc[rt][ct][i] + bsv[ct], 0.f);
                        outb[(size_t)gr * 128 + cbase + ct * 16 + ln] = f2b(xv);
                    }
                }
            }
        }
    } else {
        __syncthreads();   // all stage-1 reads of Xs/Ws complete
        // epilogue x -> Xs (overwrite); stage Ws = W1next
#pragma unroll
        for (int rt = 0; rt < 4; ++rt) {
            int lr0 = lrbase + rt * 16 + q * 4;
#pragma unroll
            for (int i = 0; i < 4; ++i) {
                int lr = lr0 + i;
                int gr = row0 + lr;
#pragma unroll
                for (int ct = 0; ct < 4; ++ct) {
                    float xv = (gr < N_NODES) ? fmaxf(acc[rt][ct][i] + bsv[ct], 0.f) : 0.f;
                    Xs[lr * 136 + cbase + ct * 16 + ln] = f2b(xv);
                }
            }
        }
#pragma unroll
        for (int i = 0; i < 8; ++i) {
            int chunk = tid + 256 * i;
            int n = chunk >> 4;
            int k8 = (chunk & 15) * 8;
            *(bf16x8*)&Ws[n * 136 + k8] = *(const bf16x8*)&Wt1n[n * 128 + k8];
        }
        __syncthreads();

#pragma unroll
        for (int rt = 0; rt < 4; ++rt)
#pragma unroll
            for (int ct = 0; ct < 4; ++ct) acc[rt][ct] = z4;

#pragma unroll
        for (int ks = 0; ks < 4; ++ks) {
            int ko = ks * 32 + q * 8;
            bf16x8 af[4], bfr[4];
#pragma unroll
            for (int rt = 0; rt < 4; ++rt)
                af[rt] = *(bf16x8*)&Xs[(lrbase + rt * 16 + ln) * 136 + ko];
#pragma unroll
            for (int ct = 0; ct < 4; ++ct)
                bfr[ct] = *(bf16x8*)&Ws[(cbase + ct * 16 + ln) * 136 + ko];
#pragma unroll
            for (int rt = 0; rt < 4; ++rt)
#pragma unroll
                for (int ct = 0; ct < 4; ++ct)
                    acc[rt][ct] = __builtin_amdgcn_mfma_f32_16x16x32_bf16(af[rt], bfr[ct],
                                                                          acc[rt][ct], 0, 0, 0);
        }
#pragma unroll
        for (int rt = 0; rt < 4; ++rt) {
            int gr0 = row0 + lrbase + rt * 16 + q * 4;
#pragma unroll
            for (int i = 0; i < 4; ++i) {
                int gr = gr0 + i;
                if (gr < N_NODES) {
#pragma unroll
                    for (int ct = 0; ct < 4; ++ct)
                        outb[(size_t)gr * 128 + cbase + ct * 16 + ln] = f2b(acc[rt][ct][i]);
                }
            }
        }
    }
}

// ---- fused pool + head: block = graph (512 thr). Pool: 8 node-slices x 64
// dword lanes (2 bf16 features each). MLP1: 4 k-slices x 32. MLP2: 8 x 16.
// LDS tree reductions; gstart precomputed (no binary search).
__global__ __launch_bounds__(512) void k_poolhead(const unsigned short* __restrict__ xb,
                                                  const int* __restrict__ gstart,
                                                  const float* __restrict__ fW1,
                                                  const float* __restrict__ fb1,
                                                  const float* __restrict__ fW2,
                                                  const float* __restrict__ fb2,
                                                  float* __restrict__ out) {
    __shared__ float gs[128];
    __shared__ float hs[128];
    __shared__ float redx[512];
    __shared__ float redy[512];
    int b = blockIdx.x, tid = threadIdx.x;
    int s = gstart[b], e = gstart[b + 1];
    int d = tid & 63;          // dword (features 2d, 2d+1)
    int sl = tid >> 6;         // 8 node slices
    const unsigned int* x1 = (const unsigned int*)xb;
    float ax = 0.f, ay = 0.f;
    for (int i = s + sl; i < e; i += 8) {
        unsigned int v = x1[(size_t)i * 64 + d];
        ax += __uint_as_float(v << 16);
        ay += __uint_as_float(v & 0xffff0000u);
    }
    redx[tid] = ax;
    redy[tid] = ay;
    __syncthreads();
    if (tid < 64) {
        float sx = 0.f, sy = 0.f;
#pragma unroll
        for (int j = 0; j < 8; ++j) {
            sx += redx[tid + 64 * j];
            sy += redy[tid + 64 * j];
        }
        gs[2 * tid] = sx;
        gs[2 * tid + 1] = sy;
    }
    __syncthreads();
    // MLP1: h = relu(gs @ fW1 + fb1), 4 k-slices x 32
    {
        int f = tid & 127, s4 = tid >> 7;
        float p = 0.f;
        int k0 = s4 * 32;
#pragma unroll 8
        for (int k = k0; k < k0 + 32; ++k) p += gs[k] * fW1[k * 128 + f];
        redx[tid] = p;
    }
    __syncthreads();
    if (tid < 128) {
        float a = fb1[tid] + redx[tid] + redx[tid + 128] + redx[tid + 256] + redx[tid + 384];
        hs[tid] = fmaxf(a, 0.f);
    }
    __syncthreads();
    // MLP2: out = hs @ fW2 + fb2, 8 k-slices x 16
    {
        int o = tid & 63, s8 = tid >> 6;
        float p = 0.f;
        int k0 = s8 * 16;
#pragma unroll 8
        for (int k = k0; k < k0 + 16; ++k) p += hs[k] * fW2[k * 64 + o];
        redx[tid] = p;
    }
    __syncthreads();
    if (tid < 64) {
        float o = fb2[tid];
#pragma unroll
        for (int j = 0; j < 8; ++j) o += redx[tid + 64 * j];
        out[(size_t)b * 64 + tid] = o;
    }
}

extern "C" void kernel_launch(void* const* d_in, const int* in_sizes, int n_in,
                              void* d_out, int out_size, void* d_ws, size_t ws_size,
                              hipStream_t stream) {
    const float* x     = (const float*)d_in[0];
    const void*  ei    = d_in[1];
    const void*  batch = d_in[2];
    const float* W1    = (const float*)d_in[3];
    const float* gamma = (const float*)d_in[5];
    const float* beta  = (const float*)d_in[6];
    const float* W2    = (const float*)d_in[7];
    const float* b2    = (const float*)d_in[8];
    const float* fW1   = (const float*)d_in[9];
    const float* fb1   = (const float*)d_in[10];
    const float* fW2   = (const float*)d_in[11];
    const float* fb2   = (const float*)d_in[12];
    float* out = (float*)d_out;

    // workspace layout; stats+bcnt contiguous for a single zero-fill memset.
    unsigned short* ub = (unsigned short*)d_ws;                    // 12.8M us
    unsigned short* zb = ub + (size_t)N_NODES * D;                 // 12.8M us
    unsigned short* xb = zb + (size_t)N_NODES * D;                 // 12.8M us (final x)
    float* stats = (float*)(xb + (size_t)N_NODES * D);             // NL*NREP*256 floats
    int* bcnt   = (int*)(stats + (size_t)NL * NREP * 256);         // 512 (zeroed w/ stats)
    int* rowp   = bcnt + 512;                                      // 100,004 (padded)
    int* eidx   = rowp + 100004;                                   // 1,600,000
    unsigned int* tmp = (unsigned int*)(eidx + N_EDGES);           // 1,600,000
    int* dflag  = (int*)(tmp + N_EDGES);                           // 4
    int* bbase  = dflag + 4;                                       // 512
    int* gcur   = bbase + 512;                                     // 512
    int* gstart = gcur + 512;                                      // 1028 (N_GRAPHS+1 pad)
    unsigned short* Wt = (unsigned short*)(gstart + 1028);         // 6*16384 us

    hipMemsetAsync(stats, 0, ((size_t)NL * NREP * 256 + 512) * sizeof(int), stream);

    k_wprep<<<dim3(128, 2 * NL), 128, 0, stream>>>(W1, W2, Wt, ei, dflag);
    k_gbound<<<(N_NODES + 255) / 256, 256, 0, stream>>>(batch, dflag, gstart);
    const int part_grid = (N_EDGES + EPB - 1) / EPB;  // 391
    k_bcount<<<part_grid, 256, 0, stream>>>(ei, dflag, bcnt);
    k_bscan<<<1, 256, 0, stream>>>(bcnt, bbase, gcur, rowp);
    k_part<<<part_grid, 256, 0, stream>>>(ei, dflag, gcur, tmp);
    k_fscat<<<NB, 256, 0, stream>>>(tmp, bbase, rowp, eidx);

    const int gemm_grid = (N_NODES + 127) / 128;  // 782

    k_gemm0<<<gemm_grid, 256, 0, stream>>>(x, Wt, ub);
    for (int l = 0; l < NL; ++l) {
        k_agz<<<(N_NODES + 63) / 64, 1024, 0, stream>>>(ub, rowp, eidx, zb,
                                                        stats + (size_t)l * NREP * 256);
        if (l < NL - 1) {
            k_gemm2f<0><<<gemm_grid, 256, 0, stream>>>(
                zb, Wt + (size_t)(NL + l) * D * D, Wt + (size_t)(l + 1) * D * D,
                b2 + (size_t)l * D, stats + (size_t)l * NREP * 256,
                gamma + (size_t)l * D, beta + (size_t)l * D, ub);
        } else {
            k_gemm2f<1><<<gemm_grid, 256, 0, stream>>>(
                zb, Wt + (size_t)(NL + l) * D * D, nullptr,
                b2 + (size_t)l * D, stats + (size_t)l * NREP * 256,
                gamma + (size_t)l * D, beta + (size_t)l * D, xb);
        }
    }

    k_poolhead<<<N_GRAPHS, 512, 0, stream>>>(xb, gstart, fW1, fb1, fW2, fb2, out);
}

// Round 13
// 482.637 us; speedup vs baseline: 1.6618x; 1.6618x over previous
//
#include <hip/hip_runtime.h>

#define N_NODES 100000
#define N_EDGES 1600000
#define N_GRAPHS 1024
#define D 128
#define NL 3
#define BN_EPS 1e-5f
#define BG 196                                  // dst nodes per bucket
#define NB ((N_NODES + BG - 1) / BG)            // 511 buckets
#define EPB 4096                                // edges per partition block
#define NREP 64                                 // stats replica banks

typedef __attribute__((ext_vector_type(8))) short bf16x8;
typedef __attribute__((ext_vector_type(4))) float f32x4;

__device__ __forceinline__ unsigned short f2b(float f) {
    unsigned int u = __float_as_uint(f);
    u += 0x7fff + ((u >> 16) & 1);   // round to nearest even
    return (unsigned short)(u >> 16);
}
__device__ __forceinline__ float b2f(unsigned short b) {
    return __uint_as_float(((unsigned int)b) << 16);
}

__device__ __forceinline__ int geti(const void* p, long long i, int f64) {
    return f64 ? (int)((const long long*)p)[i] : ((const int*)p)[i];
}

// ------- weight prep: Wt[m][n][k] = bf16(W[m][k][n]); block(0,0) also detects
// the edge-index dtype (int64 vs int32) into *flag.
__global__ void k_wprep(const float* __restrict__ W1, const float* __restrict__ W2,
                        unsigned short* __restrict__ Wt, const void* ei, int* flag) {
    int m = blockIdx.y;
    int k = blockIdx.x;
    int n = threadIdx.x;
    const float* src = (m < NL) ? (W1 + (size_t)m * D * D) : (W2 + (size_t)(m - NL) * D * D);
    Wt[(size_t)m * D * D + n * D + k] = f2b(src[k * D + n]);
    if (blockIdx.x == 0 && blockIdx.y == 0 && threadIdx.x < 64) {
        int t = threadIdx.x;
        const int* p = (const int*)ei;
        int acc = p[2 * t + 1] | p[2 * (t + 64) + 1];
        unsigned long long b = __ballot(acc != 0);
        if (t == 0) *flag = (b == 0ULL) ? 1 : 0;
    }
}

// ---- graph boundaries from sorted batch: gstart[g] = first node of graph g;
// gstart[N_GRAPHS] = N_NODES. Range-fill at transitions handles empty graphs.
__global__ __launch_bounds__(256) void k_gbound(const void* batch, const int* __restrict__ flag,
                                                int* __restrict__ gstart) {
    int f = *flag;
    int i = blockIdx.x * 256 + threadIdx.x;
    if (i >= N_NODES) return;
    int b1 = geti(batch, i, f);
    if (i == 0) {
        for (int g = 0; g <= b1; ++g) gstart[g] = 0;
    } else {
        int b0 = geti(batch, i - 1, f);
        for (int g = b0 + 1; g <= b1; ++g) gstart[g] = i;
    }
    if (i == N_NODES - 1) {
        for (int g = b1 + 1; g <= N_GRAPHS; ++g) gstart[g] = N_NODES;
    }
}

// ---- bucket-level edge count: LDS hist over 511 buckets, one flush/block ----
__global__ __launch_bounds__(256) void k_bcount(const void* ei, const int* __restrict__ flag,
                                                int* __restrict__ bcnt) {
    __shared__ int hist[NB];
    int tid = threadIdx.x;
    long long e0 = (long long)blockIdx.x * EPB;
    int f = *flag;
    for (int b = tid; b < NB; b += 256) hist[b] = 0;
    __syncthreads();
#pragma unroll
    for (int i = 0; i < EPB / 256; ++i) {
        long long e = e0 + i * 256 + tid;
        if (e < N_EDGES) {
            int d = geti(ei, (long long)N_EDGES + e, f);
            atomicAdd(&hist[d / BG], 1);
        }
    }
    __syncthreads();
    for (int b = tid; b < NB; b += 256) {
        int h = hist[b];
        if (h) atomicAdd(&bcnt[b], h);
    }
}

// ---- bucket prefix scan (511 entries, 1 block): bbase/gcur; rowp[N]=E ----
__global__ void k_bscan(const int* __restrict__ bcnt, int* __restrict__ bbase,
                        int* __restrict__ gcur, int* __restrict__ rowp) {
    __shared__ int wtot[4];
    int tid = threadIdx.x;           // 256
    int lane = tid & 63, w = tid >> 6;
    int i0 = 2 * tid, i1 = 2 * tid + 1;
    int a = (i0 < NB) ? bcnt[i0] : 0;
    int b = (i1 < NB) ? bcnt[i1] : 0;
    int p = a + b;
    int incl = p;
    for (int off = 1; off < 64; off <<= 1) {
        int v = __shfl_up(incl, off, 64);
        if (lane >= off) incl += v;
    }
    if (lane == 63) wtot[w] = incl;
    __syncthreads();
    int woff = 0;
    for (int w2 = 0; w2 < w; ++w2) woff += wtot[w2];
    int ex = woff + incl - p;
    if (i0 <= NB) { bbase[i0] = ex; gcur[i0] = ex; }
    if (i1 <= NB) { bbase[i1] = ex + a; gcur[i1] = ex + a; }
    if (tid == 0) rowp[N_NODES] = N_EDGES;
}

// ---- partition edges into NB coarse dst-buckets, packed (dl<<17|src) --------
__global__ __launch_bounds__(256) void k_part(const void* ei, const int* __restrict__ flag,
                                              int* __restrict__ gcur,
                                              unsigned int* __restrict__ tmp) {
    __shared__ int hist[NB + 1];
    __shared__ int cur[NB + 1];
    int tid = threadIdx.x;
    long long e0 = (long long)blockIdx.x * EPB;
    int f = *flag;
    for (int b = tid; b < NB; b += 256) hist[b] = 0;
    __syncthreads();
#pragma unroll
    for (int i = 0; i < EPB / 256; ++i) {
        long long e = e0 + i * 256 + tid;
        if (e < N_EDGES) {
            int d = geti(ei, (long long)N_EDGES + e, f);
            atomicAdd(&hist[d / BG], 1);
        }
    }
    __syncthreads();
    for (int b = tid; b < NB; b += 256) {
        int h = hist[b];
        cur[b] = h ? atomicAdd(&gcur[b], h) : 0;
    }
    __syncthreads();
#pragma unroll
    for (int i = 0; i < EPB / 256; ++i) {
        long long e = e0 + i * 256 + tid;
        if (e < N_EDGES) {
            int d = geti(ei, (long long)N_EDGES + e, f);
            int s = geti(ei, e, f);
            int b = d / BG;
            int pos = atomicAdd(&cur[b], 1);
            tmp[pos] = ((unsigned int)(d - b * BG) << 17) | (unsigned int)s;
        }
    }
}

// ---- per-bucket: build deg in LDS, local prefix -> rowp, scatter to eidx ----
__global__ __launch_bounds__(256) void k_fscat(const unsigned int* __restrict__ tmp,
                                               const int* __restrict__ bbase,
                                               int* __restrict__ rowp,
                                               int* __restrict__ eidx) {
    __shared__ int deg[BG];
    __shared__ int cur[BG];
    __shared__ int wtot[4];
    __shared__ int s_se[2];
    int b = blockIdx.x;
    int nb = b * BG;
    int nn = min(BG, N_NODES - nb);
    int tid = threadIdx.x;
    int lane = tid & 63, w = tid >> 6;
    if (tid < nn) deg[tid] = 0;
    if (tid == 0) s_se[0] = bbase[b];
    if (tid == 1) s_se[1] = bbase[b + 1];
    __syncthreads();
    int s = s_se[0], e = s_se[1];
    // pass 1: per-dst counts
    for (int t = s + tid; t < e; t += 256) atomicAdd(&deg[tmp[t] >> 17], 1);
    __syncthreads();
    // exclusive prefix over nn (<=196) entries, 4-wave shuffle scan
    int val = (tid < nn) ? deg[tid] : 0;
    int incl = val;
    for (int off = 1; off < 64; off <<= 1) {
        int v = __shfl_up(incl, off, 64);
        if (lane >= off) incl += v;
    }
    if (lane == 63) wtot[w] = incl;
    __syncthreads();
    int woff = 0;
    for (int w2 = 0; w2 < w; ++w2) woff += wtot[w2];
    int ex = s + woff + incl - val;
    if (tid < nn) {
        cur[tid] = ex;
        rowp[nb + tid] = ex;
    }
    __syncthreads();
    // pass 2: scatter within bucket (L2-local)
    for (int t = s + tid; t < e; t += 256) {
        unsigned int u = tmp[t];
        int dl = u >> 17;
        int pos = atomicAdd(&cur[dl], 1);
        eidx[pos] = (int)(u & 0x1FFFF);
    }
}

// ---------------- GEMM0: u0 = bf16(x) @ W1_0 (fp32 A direct, W in LDS) -------
__global__ __launch_bounds__(256) void k_gemm0(const float* __restrict__ x,
                                               const unsigned short* __restrict__ Wt,
                                               unsigned short* __restrict__ ub) {
    __shared__ unsigned short Ws[128 * 136];
    int tid = threadIdx.x;
    int row0 = blockIdx.x * 128;
#pragma unroll
    for (int i = 0; i < 8; ++i) {
        int chunk = tid + 256 * i;
        int n = chunk >> 4;
        int k8 = (chunk & 15) * 8;
        *(bf16x8*)&Ws[n * 136 + k8] = *(const bf16x8*)&Wt[n * 128 + k8];
    }
    __syncthreads();

    int w = tid >> 6, lane = tid & 63, q = lane >> 4, ln = lane & 15;
    int rbase = row0 + (w & 1) * 64, cbase = (w >> 1) * 64;

    f32x4 acc[4][4];
    f32x4 z4 = {0.f, 0.f, 0.f, 0.f};
#pragma unroll
    for (int rt = 0; rt < 4; ++rt)
#pragma unroll
        for (int ct = 0; ct < 4; ++ct) acc[rt][ct] = z4;

#pragma unroll
    for (int ks = 0; ks < 4; ++ks) {
        int ko = ks * 32 + q * 8;
        bf16x8 af[4];
#pragma unroll
        for (int rt = 0; rt < 4; ++rt) {
            int row = rbase + rt * 16 + ln;
            bf16x8 v = {0, 0, 0, 0, 0, 0, 0, 0};
            if (row < N_NODES) {
                float4 p0 = *(const float4*)&x[(size_t)row * 128 + ko];
                float4 p1 = *(const float4*)&x[(size_t)row * 128 + ko + 4];
                v[0] = (short)f2b(p0.x); v[1] = (short)f2b(p0.y);
                v[2] = (short)f2b(p0.z); v[3] = (short)f2b(p0.w);
                v[4] = (short)f2b(p1.x); v[5] = (short)f2b(p1.y);
                v[6] = (short)f2b(p1.z); v[7] = (short)f2b(p1.w);
            }
            af[rt] = v;
        }
        bf16x8 bfr[4];
#pragma unroll
        for (int ct = 0; ct < 4; ++ct)
            bfr[ct] = *(bf16x8*)&Ws[(cbase + ct * 16 + ln) * 136 + ko];
#pragma unroll
        for (int rt = 0; rt < 4; ++rt)
#pragma unroll
            for (int ct = 0; ct < 4; ++ct)
                acc[rt][ct] = __builtin_amdgcn_mfma_f32_16x16x32_bf16(af[rt], bfr[ct],
                                                                      acc[rt][ct], 0, 0, 0);
    }
#pragma unroll
    for (int rt = 0; rt < 4; ++rt) {
        int gr0 = rbase + rt * 16 + q * 4;
#pragma unroll
        for (int i = 0; i < 4; ++i) {
            int gr = gr0 + i;
            if (gr < N_NODES) {
#pragma unroll
                for (int ct = 0; ct < 4; ++ct)
                    ub[(size_t)gr * 128 + cbase + ct * 16 + ln] = f2b(acc[rt][ct][i]);
            }
        }
    }
}

// ---- aggregation + fused BN stats: z = u_i + sum_j u_j; stats += (z, z^2) ---
// Round-10 gather structure (4 waves x 4 nodes, 6250 blocks, register stat
// accumulation). ZERO LDS atomics: each wave writes its 16x16 partials
// non-atomically to s_part[k][wid][c]; after the barrier each of 256 threads
// sums 4 wave-partials and issues ONE global atomic (1.6M/layer) into a
// replica bank. r12 lesson: inline LDS atomics (25.6M, esp. 16-wave shared)
// were the dominant cost, not global flush.
__global__ __launch_bounds__(256) void k_agz(const unsigned short* __restrict__ ub,
                                             const int* __restrict__ rowp,
                                             const int* __restrict__ eidx,
                                             unsigned short* __restrict__ zb,
                                             float* __restrict__ stats) {
    __shared__ float s_part[16][4][16];   // [k: 0-7 sum, 8-15 sq][wave][lane c]
    int tid = threadIdx.x;
    int wid = tid >> 6;
    int lane = tid & 63;
    int eg = lane >> 4;           // edge slot 0..3
    int c = lane & 15;            // 16B quad within row (dwords 4c..4c+3)
    const unsigned int* u1 = (const unsigned int*)ub;   // 64 dwords per row
    float st_s0 = 0.f, st_s1 = 0.f, st_s2 = 0.f, st_s3 = 0.f;
    float st_s4 = 0.f, st_s5 = 0.f, st_s6 = 0.f, st_s7 = 0.f;
    float st_q0 = 0.f, st_q1 = 0.f, st_q2 = 0.f, st_q3 = 0.f;
    float st_q4 = 0.f, st_q5 = 0.f, st_q6 = 0.f, st_q7 = 0.f;
    int base = (blockIdx.x * 4 + wid) * 4;
#pragma unroll
    for (int j = 0; j < 4; ++j) {
        int node = base + j;
        float ax0 = 0.f, ax1 = 0.f, ax2 = 0.f, ax3 = 0.f;
        float ay0 = 0.f, ay1 = 0.f, ay2 = 0.f, ay3 = 0.f;
        int s = rowp[node], e = rowp[node + 1];
        int i = s;
        for (; i + 7 < e; i += 8) {
            int p0 = eidx[i + eg];
            int p1 = eidx[i + 4 + eg];
            uint4 a = *(const uint4*)&u1[(size_t)p0 * 64 + c * 4];
            uint4 b = *(const uint4*)&u1[(size_t)p1 * 64 + c * 4];
            ax0 += __uint_as_float(a.x << 16) + __uint_as_float(b.x << 16);
            ay0 += __uint_as_float(a.x & 0xffff0000u) + __uint_as_float(b.x & 0xffff0000u);
            ax1 += __uint_as_float(a.y << 16) + __uint_as_float(b.y << 16);
            ay1 += __uint_as_float(a.y & 0xffff0000u) + __uint_as_float(b.y & 0xffff0000u);
            ax2 += __uint_as_float(a.z << 16) + __uint_as_float(b.z << 16);
            ay2 += __uint_as_float(a.z & 0xffff0000u) + __uint_as_float(b.z & 0xffff0000u);
            ax3 += __uint_as_float(a.w << 16) + __uint_as_float(b.w << 16);
            ay3 += __uint_as_float(a.w & 0xffff0000u) + __uint_as_float(b.w & 0xffff0000u);
        }
        for (; i < e; i += 4) {
            int pos = i + eg;
            int valid = pos < e;
            int p0 = eidx[valid ? pos : (e - 1)];
            uint4 a = *(const uint4*)&u1[(size_t)p0 * 64 + c * 4];
            if (valid) {
                ax0 += __uint_as_float(a.x << 16);
                ay0 += __uint_as_float(a.x & 0xffff0000u);
                ax1 += __uint_as_float(a.y << 16);
                ay1 += __uint_as_float(a.y & 0xffff0000u);
                ax2 += __uint_as_float(a.z << 16);
                ay2 += __uint_as_float(a.z & 0xffff0000u);
                ax3 += __uint_as_float(a.w << 16);
                ay3 += __uint_as_float(a.w & 0xffff0000u);
            }
        }
        // reduce 4 edge-slot groups; lanes with equal c hold the same features
#pragma unroll
        for (int off = 16; off < 64; off <<= 1) {
            ax0 += __shfl_xor(ax0, off, 64);
            ay0 += __shfl_xor(ay0, off, 64);
            ax1 += __shfl_xor(ax1, off, 64);
            ay1 += __shfl_xor(ay1, off, 64);
            ax2 += __shfl_xor(ax2, off, 64);
            ay2 += __shfl_xor(ay2, off, 64);
            ax3 += __shfl_xor(ax3, off, 64);
            ay3 += __shfl_xor(ay3, off, 64);
        }
        if (eg == 0) {
            uint4 sv = *(const uint4*)&u1[(size_t)node * 64 + c * 4];
            ax0 += __uint_as_float(sv.x << 16);
            ay0 += __uint_as_float(sv.x & 0xffff0000u);
            ax1 += __uint_as_float(sv.y << 16);
            ay1 += __uint_as_float(sv.y & 0xffff0000u);
            ax2 += __uint_as_float(sv.z << 16);
            ay2 += __uint_as_float(sv.z & 0xffff0000u);
            ax3 += __uint_as_float(sv.w << 16);
            ay3 += __uint_as_float(sv.w & 0xffff0000u);
            uint4 o;
            o.x = ((unsigned int)f2b(ay0) << 16) | f2b(ax0);
            o.y = ((unsigned int)f2b(ay1) << 16) | f2b(ax1);
            o.z = ((unsigned int)f2b(ay2) << 16) | f2b(ax2);
            o.w = ((unsigned int)f2b(ay3) << 16) | f2b(ax3);
            *(uint4*)&((unsigned int*)zb)[(size_t)node * 64 + c * 4] = o;
            // stats from the bf16-rounded stored values (matches old zstats)
            float rx, ry;
            rx = b2f((unsigned short)(o.x & 0xffffu)); ry = b2f((unsigned short)(o.x >> 16));
            st_s0 += rx; st_q0 += rx * rx; st_s1 += ry; st_q1 += ry * ry;
            rx = b2f((unsigned short)(o.y & 0xffffu)); ry = b2f((unsigned short)(o.y >> 16));
            st_s2 += rx; st_q2 += rx * rx; st_s3 += ry; st_q3 += ry * ry;
            rx = b2f((unsigned short)(o.z & 0xffffu)); ry = b2f((unsigned short)(o.z >> 16));
            st_s4 += rx; st_q4 += rx * rx; st_s5 += ry; st_q5 += ry * ry;
            rx = b2f((unsigned short)(o.w & 0xffffu)); ry = b2f((unsigned short)(o.w >> 16));
            st_s6 += rx; st_q6 += rx * rx; st_s7 += ry; st_q7 += ry * ry;
        }
    }
    // non-atomic per-wave partial write: s_part[k][wid][c]
    if (eg == 0) {
        s_part[0][wid][c] = st_s0;  s_part[1][wid][c] = st_s1;
        s_part[2][wid][c] = st_s2;  s_part[3][wid][c] = st_s3;
        s_part[4][wid][c] = st_s4;  s_part[5][wid][c] = st_s5;
        s_part[6][wid][c] = st_s6;  s_part[7][wid][c] = st_s7;
        s_part[8][wid][c] = st_q0;  s_part[9][wid][c] = st_q1;
        s_part[10][wid][c] = st_q2; s_part[11][wid][c] = st_q3;
        s_part[12][wid][c] = st_q4; s_part[13][wid][c] = st_q5;
        s_part[14][wid][c] = st_q6; s_part[15][wid][c] = st_q7;
    }
    __syncthreads();
    // flush: thread tid handles stats slot tid (f<128: sum of feature f;
    // f>=128: sumsq). feature f -> lane c=f>>3, k-index j=f&7 (+8 for sq).
    {
        int f = tid & 127;
        int k = (f & 7) + ((tid >> 7) << 3);
        int cc = f >> 3;
        float v = s_part[k][0][cc] + s_part[k][1][cc] +
                  s_part[k][2][cc] + s_part[k][3][cc];
        float* S = stats + (size_t)(blockIdx.x & (NREP - 1)) * 256;
        atomicAdd(&S[tid], v);
    }
}

// ---- GEMM2 fused: x = relu(BN(z)@W2+b2); if !LAST also u' = x@W1next -------
// BN(z) staged ONCE per element into Xs (halves BN VALU vs per-wave frag BN);
// both K-loops read A-frags via ds_read_b128. Xs is reused for x between
// stages; Ws is reused for W1next. Stats arrive in NREP replica banks.
template <int LAST>
__global__ __launch_bounds__(256) void k_gemm2f(const unsigned short* __restrict__ zb,
                                                const unsigned short* __restrict__ Wt2,
                                                const unsigned short* __restrict__ Wt1n,
                                                const float* __restrict__ b2,
                                                const float* __restrict__ stats,
                                                const float* __restrict__ gamma,
                                                const float* __restrict__ beta,
                                                unsigned short* __restrict__ outb) {
    __shared__ unsigned short Ws[128 * 136];
    __shared__ unsigned short Xs[128 * 136];
    __shared__ float s_a[128];
    __shared__ float s_b[128];

    int tid = threadIdx.x;
    int row0 = blockIdx.x * 128;

    // stage Ws = W2; compute BN scale/shift from replica banks
#pragma unroll
    for (int i = 0; i < 8; ++i) {
        int chunk = tid + 256 * i;
        int n = chunk >> 4;
        int k8 = (chunk & 15) * 8;
        *(bf16x8*)&Ws[n * 136 + k8] = *(const bf16x8*)&Wt2[n * 128 + k8];
    }
    if (tid < 128) {
        float s1 = 0.f, s2 = 0.f;
#pragma unroll 8
        for (int r = 0; r < NREP; ++r) {
            s1 += stats[(size_t)r * 256 + tid];
            s2 += stats[(size_t)r * 256 + 128 + tid];
        }
        float mu = s1 / (float)N_NODES;
        float var = s2 / (float)N_NODES - mu * mu;
        float sc = rsqrtf(var + BN_EPS) * gamma[tid];
        s_a[tid] = sc;
        s_b[tid] = beta[tid] - mu * sc;
    }
    __syncthreads();

    // stage relu(BN(z)) -> Xs, each element exactly once
#pragma unroll
    for (int i = 0; i < 8; ++i) {
        int chunk = tid + 256 * i;
        int row = chunk >> 4;
        int k8 = (chunk & 15) * 8;
        int gr = row0 + row;
        bf16x8 v = {0, 0, 0, 0, 0, 0, 0, 0};
        if (gr < N_NODES) v = *(const bf16x8*)&zb[(size_t)gr * 128 + k8];
        float4 sc0 = *(const float4*)&s_a[k8];
        float4 sc1 = *(const float4*)&s_a[k8 + 4];
        float4 sh0 = *(const float4*)&s_b[k8];
        float4 sh1 = *(const float4*)&s_b[k8 + 4];
        bf16x8 o;
        o[0] = (short)f2b(fmaxf(b2f((unsigned short)v[0]) * sc0.x + sh0.x, 0.f));
        o[1] = (short)f2b(fmaxf(b2f((unsigned short)v[1]) * sc0.y + sh0.y, 0.f));
        o[2] = (short)f2b(fmaxf(b2f((unsigned short)v[2]) * sc0.z + sh0.z, 0.f));
        o[3] = (short)f2b(fmaxf(b2f((unsigned short)v[3]) * sc0.w + sh0.w, 0.f));
        o[4] = (short)f2b(fmaxf(b2f((unsigned short)v[4]) * sc1.x + sh1.x, 0.f));
        o[5] = (short)f2b(fmaxf(b2f((unsigned short)v[5]) * sc1.y + sh1.y, 0.f));
        o[6] = (short)f2b(fmaxf(b2f((unsigned short)v[6]) * sc1.z + sh1.z, 0.f));
        o[7] = (short)f2b(fmaxf(b2f((unsigned short)v[7]) * sc1.w + sh1.w, 0.f));
        *(bf16x8*)&Xs[row * 136 + k8] = o;
    }
    __syncthreads();

    int w = tid >> 6, lane = tid & 63, q = lane >> 4, ln = lane & 15;
    int lrbase = (w & 1) * 64, cbase = (w >> 1) * 64;

    f32x4 acc[4][4];
    f32x4 z4 = {0.f, 0.f, 0.f, 0.f};
#pragma unroll
    for (int rt = 0; rt < 4; ++rt)
#pragma unroll
        for (int ct = 0; ct < 4; ++ct) acc[rt][ct] = z4;

    // stage 1 K-loop: A from Xs, B from Ws (pure ds_read + MFMA)
#pragma unroll
    for (int ks = 0; ks < 4; ++ks) {
        int ko = ks * 32 + q * 8;
        bf16x8 af[4], bfr[4];
#pragma unroll
        for (int rt = 0; rt < 4; ++rt)
            af[rt] = *(bf16x8*)&Xs[(lrbase + rt * 16 + ln) * 136 + ko];
#pragma unroll
        for (int ct = 0; ct < 4; ++ct)
            bfr[ct] = *(bf16x8*)&Ws[(cbase + ct * 16 + ln) * 136 + ko];
#pragma unroll
        for (int rt = 0; rt < 4; ++rt)
#pragma unroll
            for (int ct = 0; ct < 4; ++ct)
                acc[rt][ct] = __builtin_amdgcn_mfma_f32_16x16x32_bf16(af[rt], bfr[ct],
                                                                      acc[rt][ct], 0, 0, 0);
    }

    float bsv[4];
#pragma unroll
    for (int ct = 0; ct < 4; ++ct) bsv[ct] = b2[cbase + ct * 16 + ln];

    if (LAST) {
        // epilogue straight to global
#pragma unroll
        for (int rt = 0; rt < 4; ++rt) {
            int gr0 = row0 + lrbase + rt * 16 + q * 4;
#pragma unroll
            for (int i = 0; i < 4; ++i) {
                int gr = gr0 + i;
                if (gr < N_NODES) {
#pragma unroll
                    for (int ct = 0; ct < 4; ++ct) {
                        float xv = fmaxf(acc[rt][ct][i] + bsv[ct], 0.f);
                        outb[(size_t)gr * 128 + cbase + ct * 16 + ln] = f2b(xv);
                    }
                }
            }
        }
    } else {
        __syncthreads();   // all stage-1 reads of Xs/Ws complete
        // epilogue x -> Xs (overwrite); stage Ws = W1next
#pragma unroll
        for (int rt = 0; rt < 4; ++rt) {
            int lr0 = lrbase + rt * 16 + q * 4;
#pragma unroll
            for (int i = 0; i < 4; ++i) {
                int lr = lr0 + i;
                int gr = row0 + lr;
#pragma unroll
                for (int ct = 0; ct < 4; ++ct) {
                    float xv = (gr < N_NODES) ? fmaxf(acc[rt][ct][i] + bsv[ct], 0.f) : 0.f;
                    Xs[lr * 136 + cbase + ct * 16 + ln] = f2b(xv);
                }
            }
        }
#pragma unroll
        for (int i = 0; i < 8; ++i) {
            int chunk = tid + 256 * i;
            int n = chunk >> 4;
            int k8 = (chunk & 15) * 8;
            *(bf16x8*)&Ws[n * 136 + k8] = *(const bf16x8*)&Wt1n[n * 128 + k8];
        }
        __syncthreads();

#pragma unroll
        for (int rt = 0; rt < 4; ++rt)
#pragma unroll
            for (int ct = 0; ct < 4; ++ct) acc[rt][ct] = z4;

#pragma unroll
        for (int ks = 0; ks < 4; ++ks) {
            int ko = ks * 32 + q * 8;
            bf16x8 af[4], bfr[4];
#pragma unroll
            for (int rt = 0; rt < 4; ++rt)
                af[rt] = *(bf16x8*)&Xs[(lrbase + rt * 16 + ln) * 136 + ko];
#pragma unroll
            for (int ct = 0; ct < 4; ++ct)
                bfr[ct] = *(bf16x8*)&Ws[(cbase + ct * 16 + ln) * 136 + ko];
#pragma unroll
            for (int rt = 0; rt < 4; ++rt)
#pragma unroll
                for (int ct = 0; ct < 4; ++ct)
                    acc[rt][ct] = __builtin_amdgcn_mfma_f32_16x16x32_bf16(af[rt], bfr[ct],
                                                                          acc[rt][ct], 0, 0, 0);
        }
#pragma unroll
        for (int rt = 0; rt < 4; ++rt) {
            int gr0 = row0 + lrbase + rt * 16 + q * 4;
#pragma unroll
            for (int i = 0; i < 4; ++i) {
                int gr = gr0 + i;
                if (gr < N_NODES) {
#pragma unroll
                    for (int ct = 0; ct < 4; ++ct)
                        outb[(size_t)gr * 128 + cbase + ct * 16 + ln] = f2b(acc[rt][ct][i]);
                }
            }
        }
    }
}

// ---- fused pool + head: block = graph (512 thr). Pool: 8 node-slices x 64
// dword lanes (2 bf16 features each). MLP1: 4 k-slices x 32. MLP2: 8 x 16.
// LDS tree reductions; gstart precomputed (no binary search).
__global__ __launch_bounds__(512) void k_poolhead(const unsigned short* __restrict__ xb,
                                                  const int* __restrict__ gstart,
                                                  const float* __restrict__ fW1,
                                                  const float* __restrict__ fb1,
                                                  const float* __restrict__ fW2,
                                                  const float* __restrict__ fb2,
                                                  float* __restrict__ out) {
    __shared__ float gs[128];
    __shared__ float hs[128];
    __shared__ float redx[512];
    __shared__ float redy[512];
    int b = blockIdx.x, tid = threadIdx.x;
    int s = gstart[b], e = gstart[b + 1];
    int d = tid & 63;          // dword (features 2d, 2d+1)
    int sl = tid >> 6;         // 8 node slices
    const unsigned int* x1 = (const unsigned int*)xb;
    float ax = 0.f, ay = 0.f;
    for (int i = s + sl; i < e; i += 8) {
        unsigned int v = x1[(size_t)i * 64 + d];
        ax += __uint_as_float(v << 16);
        ay += __uint_as_float(v & 0xffff0000u);
    }
    redx[tid] = ax;
    redy[tid] = ay;
    __syncthreads();
    if (tid < 64) {
        float sx = 0.f, sy = 0.f;
#pragma unroll
        for (int j = 0; j < 8; ++j) {
            sx += redx[tid + 64 * j];
            sy += redy[tid + 64 * j];
        }
        gs[2 * tid] = sx;
        gs[2 * tid + 1] = sy;
    }
    __syncthreads();
    // MLP1: h = relu(gs @ fW1 + fb1), 4 k-slices x 32
    {
        int f = tid & 127, s4 = tid >> 7;
        float p = 0.f;
        int k0 = s4 * 32;
#pragma unroll 8
        for (int k = k0; k < k0 + 32; ++k) p += gs[k] * fW1[k * 128 + f];
        redx[tid] = p;
    }
    __syncthreads();
    if (tid < 128) {
        float a = fb1[tid] + redx[tid] + redx[tid + 128] + redx[tid + 256] + redx[tid + 384];
        hs[tid] = fmaxf(a, 0.f);
    }
    __syncthreads();
    // MLP2: out = hs @ fW2 + fb2, 8 k-slices x 16
    {
        int o = tid & 63, s8 = tid >> 6;
        float p = 0.f;
        int k0 = s8 * 16;
#pragma unroll 8
        for (int k = k0; k < k0 + 16; ++k) p += hs[k] * fW2[k * 64 + o];
        redx[tid] = p;
    }
    __syncthreads();
    if (tid < 64) {
        float o = fb2[tid];
#pragma unroll
        for (int j = 0; j < 8; ++j) o += redx[tid + 64 * j];
        out[(size_t)b * 64 + tid] = o;
    }
}

extern "C" void kernel_launch(void* const* d_in, const int* in_sizes, int n_in,
                              void* d_out, int out_size, void* d_ws, size_t ws_size,
                              hipStream_t stream) {
    const float* x     = (const float*)d_in[0];
    const void*  ei    = d_in[1];
    const void*  batch = d_in[2];
    const float* W1    = (const float*)d_in[3];
    const float* gamma = (const float*)d_in[5];
    const float* beta  = (const float*)d_in[6];
    const float* W2    = (const float*)d_in[7];
    const float* b2    = (const float*)d_in[8];
    const float* fW1   = (const float*)d_in[9];
    const float* fb1   = (const float*)d_in[10];
    const float* fW2   = (const float*)d_in[11];
    const float* fb2   = (const float*)d_in[12];
    float* out = (float*)d_out;

    // workspace layout; stats+bcnt contiguous for a single zero-fill memset.
    unsigned short* ub = (unsigned short*)d_ws;                    // 12.8M us
    unsigned short* zb = ub + (size_t)N_NODES * D;                 // 12.8M us
    unsigned short* xb = zb + (size_t)N_NODES * D;                 // 12.8M us (final x)
    float* stats = (float*)(xb + (size_t)N_NODES * D);             // NL*NREP*256 floats
    int* bcnt   = (int*)(stats + (size_t)NL * NREP * 256);         // 512 (zeroed w/ stats)
    int* rowp   = bcnt + 512;                                      // 100,004 (padded)
    int* eidx   = rowp + 100004;                                   // 1,600,000
    unsigned int* tmp = (unsigned int*)(eidx + N_EDGES);           // 1,600,000
    int* dflag  = (int*)(tmp + N_EDGES);                           // 4
    int* bbase  = dflag + 4;                                       // 512
    int* gcur   = bbase + 512;                                     // 512
    int* gstart = gcur + 512;                                      // 1028 (N_GRAPHS+1 pad)
    unsigned short* Wt = (unsigned short*)(gstart + 1028);         // 6*16384 us

    hipMemsetAsync(stats, 0, ((size_t)NL * NREP * 256 + 512) * sizeof(int), stream);

    k_wprep<<<dim3(128, 2 * NL), 128, 0, stream>>>(W1, W2, Wt, ei, dflag);
    k_gbound<<<(N_NODES + 255) / 256, 256, 0, stream>>>(batch, dflag, gstart);
    const int part_grid = (N_EDGES + EPB - 1) / EPB;  // 391
    k_bcount<<<part_grid, 256, 0, stream>>>(ei, dflag, bcnt);
    k_bscan<<<1, 256, 0, stream>>>(bcnt, bbase, gcur, rowp);
    k_part<<<part_grid, 256, 0, stream>>>(ei, dflag, gcur, tmp);
    k_fscat<<<NB, 256, 0, stream>>>(tmp, bbase, rowp, eidx);

    const int gemm_grid = (N_NODES + 127) / 128;  // 782

    k_gemm0<<<gemm_grid, 256, 0, stream>>>(x, Wt, ub);
    for (int l = 0; l < NL; ++l) {
        k_agz<<<N_NODES / 16, 256, 0, stream>>>(ub, rowp, eidx, zb,
                                                stats + (size_t)l * NREP * 256);
        if (l < NL - 1) {
            k_gemm2f<0><<<gemm_grid, 256, 0, stream>>>(
                zb, Wt + (size_t)(NL + l) * D * D, Wt + (size_t)(l + 1) * D * D,
                b2 + (size_t)l * D, stats + (size_t)l * NREP * 256,
                gamma + (size_t)l * D, beta + (size_t)l * D, ub);
        } else {
            k_gemm2f<1><<<gemm_grid, 256, 0, stream>>>(
                zb, Wt + (size_t)(NL + l) * D * D, nullptr,
                b2 + (size_t)l * D, stats + (size_t)l * NREP * 256,
                gamma + (size_t)l * D, beta + (size_t)l * D, xb);
        }
    }

    k_poolhead<<<N_GRAPHS, 512, 0, stream>>>(xb, gstart, fW1, fb1, fW2, fb2, out);
}